// Round 6
// baseline (30.064 us; speedup 1.0000x reference)
//
#include <hip/hip_runtime.h>

#define N_LAYERS 512
#define DEL_Z (0.9f / 512.0f)
#define NMACRO (N_LAYERS / 32)    // 16 macro-groups of 32 layers

// Recurrence (exact algebra of the reference), carrying t = Re + inv1(l):
//   e  = c0 + 2*DEL_Z*om*Im
//   u  = e*t + d1                      ( = Rn + inv1(l) )
//   t' = u + dl                        ( dl = inv1(l+1) - inv1(l) )
//   Im'= c0*Im + DEL_Z*om*(Im^2 - u^2 + c3) + c4p*(-1/om)
// with per-layer constants
//   c0  = 2 - b2/b1
//   d1  = -DEL_Z*inv2,   inv1 = 1/(PiT*(1-z)), inv2 = inv1/(1-z)
//   dl  = inv1(l+1) - inv1(l)
//   c3  = inv1^2 - inv2/PiT + 1/b1^2
//   c4p = DEL_Z*z^2/b1                  (MU^2 == 1)
// Output: Re_f = t_final - inv1(512).
//
// Constants are LANE-DISTRIBUTED in LDS (8 floats/layer): one per-lane
// ds_read_b128 delivers 32 layers per wave (1 KB vs 40 KB broadcast —
// R1/R5 were LDS return-bus byte-bound at ~120 cy/layer/CU). Per layer,
// 5 v_readlane_b32 (compile-time lanes) lift them into SGPRs, feeding
// FMAs as scalar operands (max 1 SGPR per VALU op respected).

__device__ __forceinline__ float rl(float v, int lane) {
    return __int_as_float(__builtin_amdgcn_readlane(__float_as_int(v), lane));
}

__global__ __launch_bounds__(256) void metric_scan_kernel(
    const float* __restrict__ Re_s, const float* __restrict__ Im_s,
    const float* __restrict__ omega, const float* __restrict__ PiT_p,
    const float* __restrict__ B, float* __restrict__ out, int n)
{
    // layer l -> floats [ (l>>5)*256 + (l&31)*8 , +8 ): {c0,d1,dl,c3,c4p,pad*3}
    // lane 2m of macro-group G reads {c0,d1,dl,c3}; lane 2m+1 reads {c4p,...}
    __shared__ float cls[N_LAYERS * 8];    // 16 KB

    const float PiT = PiT_p[0];
    for (int l = threadIdx.x; l < N_LAYERS; l += 256) {
        const float z     = DEL_Z * (float)l;          // Z_INI == 0
        const float b1    = B[l];
        const float b2    = B[l + 1];
        const float omz   = 1.0f - z;
        const float inv1  = 1.0f / (PiT * omz);
        const float inv2  = inv1 / omz;
        const float zn    = DEL_Z * (float)(l + 1);
        const float inv1n = 1.0f / (PiT * (1.0f - zn));
        const float g     = 1.0f - b2 / b1;
        float* p = cls + ((l >> 5) * 256 + (l & 31) * 8);
        p[0] = 1.0f + g;                                    // c0
        p[1] = -DEL_Z * inv2;                               // d1
        p[2] = inv1n - inv1;                                // dl
        p[3] = inv1 * inv1 - inv2 / PiT + 1.0f / (b1 * b1); // c3
        p[4] = DEL_Z * z * z / b1;                          // c4p
    }
    __syncthreads();

    const int i = blockIdx.x * 256 + threadIdx.x;
    float Im = Im_s[i];
    const float om    = omega[i];
    const float dzom  = DEL_Z * om;
    const float dz2om = 2.0f * dzom;
    const float niom  = -1.0f / om;
    float t = Re_s[i] + 1.0f / PiT;        // t_0 = Re + inv1(0), z_0 = 0

    const float4* cf4 = (const float4*)cls;
    const int lane = threadIdx.x & 63;

    float4 va = cf4[lane];                 // macro-group 0
    for (int G = 0; G < NMACRO; ++G) {
        const int Gn = (G + 1 < NMACRO) ? G + 1 : NMACRO - 1;   // clamp, no OOB
        float4 vb = cf4[Gn * 64 + lane];   // prefetch next group (double buffer)
        #pragma unroll
        for (int m = 0; m < 32; ++m) {
            const float c0  = rl(va.x, 2 * m);
            const float d1  = rl(va.y, 2 * m);
            const float dl  = rl(va.z, 2 * m);
            const float c3  = rl(va.w, 2 * m);
            const float c4p = rl(va.x, 2 * m + 1);
            const float e = fmaf(dz2om, Im, c0);
            const float u = fmaf(e, t, d1);
            float s = fmaf(Im, Im, c3);
            const float q = c4p * niom;
            const float b = fmaf(c0, Im, q);
            s = fmaf(-u, u, s);
            t = u + dl;
            Im = fmaf(dzom, s, b);
        }
        va = vb;
    }

    // Re_f = t_final - inv1(512)
    const float zend = DEL_Z * 512.0f;
    const float Re_f = t - 1.0f / (PiT * (1.0f - zend));

    out[i]     = Re_f;
    out[n + i] = Im;
}

extern "C" void kernel_launch(void* const* d_in, const int* in_sizes, int n_in,
                              void* d_out, int out_size, void* d_ws, size_t ws_size,
                              hipStream_t stream)
{
    const float* Re_s  = (const float*)d_in[0];
    const float* Im_s  = (const float*)d_in[1];
    const float* omega = (const float*)d_in[2];
    const float* PiT   = (const float*)d_in[3];
    const float* B     = (const float*)d_in[4];
    float* out = (float*)d_out;
    const int n = in_sizes[0];                  // 131072
    metric_scan_kernel<<<n / 256, 256, 0, stream>>>(Re_s, Im_s, omega, PiT, B, out, n);
}